// Round 14
// baseline (941.676 us; speedup 1.0000x reference)
//
#include <hip/hip_runtime.h>
#include <hip/hip_fp16.h>

// Bidirectional char-LSTM + masked max-pool via MFMA, operand-swapped,
// CH=1 with 16x-duplicated B-columns, role-split activation (DPP xor8),
// dim-pair-packed writeback (DPP xor1), 2 BLOCKS PER CU.
// 512 blocks = 2 dirs x 256 chains; 8 waves x 512 threads.
// R11-R13 lesson: per-step wall (~2000cyc) is serial-path-bound and constant
// vs per-CU work; waves_per_eu(2,2)'s max capped residency at 1 block/CU.
// Fix: CH=1 halves per-block work, 512 blocks + waves_per_eu(4,4) (VGPR<=128)
// -> 2 co-resident blocks/CU whose serial paths interleave.
// Lane map: l15 = q(2b) | spare(1b) | role(1b); role pair = l15^8 (DPP
// row_ror:8), hh valid in ALL lanes (B role computes sig(o)*tanh(cc_A)).
// Writeback: DPP quad_perm xor1 packs (h[even dim],h[odd dim]) into one u32;
// each of 8 holder-lanes writes 2 aligned ds_write_b32 (16 cols total).
// Per step: D'[512 gates][16 cols] = W[512][192] x H[192][16] via
// mfma_f32_16x16x32_f16; W static in VGPRs (24 f16x8/wave); H in LDS
// fragment-ordered (lane l reads bytes [l*16,l*16+16) -> conflict-free).
// One barrier per step.

#define TT 512

typedef _Float16 f16;
typedef _Float16 f16x8 __attribute__((ext_vector_type(8)));
typedef float f32x4 __attribute__((ext_vector_type(4)));
typedef unsigned int u32;
typedef unsigned short u16;

static __device__ __forceinline__ u32 packh2(float lo, float hi) {
    union { struct { f16 x, y; } h; u32 u; } cv;
    cv.h.x = (f16)lo; cv.h.y = (f16)hi;
    return cv.u;
}
static __device__ __forceinline__ float fexp(float x) {
    return __builtin_amdgcn_exp2f(x * 1.44269504088896341f);
}
static __device__ __forceinline__ float frcp(float x) {
    return __builtin_amdgcn_rcpf(x);
}
static __device__ __forceinline__ float sigf(float x) {
    return frcp(1.f + fexp(-x));
}
static __device__ __forceinline__ float xor8(float x) {
    // lane <-> lane^8: DPP row_ror:8 (rotate by 8 within rows of 16 == xor 8)
    union { float f; int i; } c; c.f = x;
    c.i = __builtin_amdgcn_mov_dpp(c.i, 0x128, 0xF, 0xF, false);
    return c.f;
}
static __device__ __forceinline__ float xor1(float x) {
    // lane <-> lane^1: DPP quad_perm(1,0,3,2) = 0xB1
    union { float f; int i; } c; c.f = x;
    c.i = __builtin_amdgcn_mov_dpp(c.i, 0xB1, 0xF, 0xF, false);
    return c.f;
}
static __device__ __forceinline__ float sel4(f32x4 v, int q) {
    // q in 0..3, compile-time indices in each arm (rule #20: no dyn index)
    return (q & 2) ? ((q & 1) ? v[3] : v[2]) : ((q & 1) ? v[1] : v[0]);
}

__global__ __attribute__((amdgpu_flat_work_group_size(512, 512),
                          amdgpu_waves_per_eu(4, 4)))
void bilstm_mfma_ch1_kernel(const int* __restrict__ idx,
                            const float* __restrict__ masks,
                            const float* __restrict__ emb,
                            const float* __restrict__ Wih_f, const float* __restrict__ Whh_f,
                            const float* __restrict__ bih_f, const float* __restrict__ bhh_f,
                            const float* __restrict__ Wih_b, const float* __restrict__ Whh_b,
                            const float* __restrict__ bih_b, const float* __restrict__ bhh_b,
                            float* __restrict__ out)
{
    // Hbuf[buf][kt][c4k][col][j]: value = H[k = kt*32 + c4k*8 + j][col] fp16;
    // all 16 cols are copies of the single chain.
    __shared__ __align__(16) unsigned char Hbuf[2][6 * 1024];  // 12 KB
    __shared__ u16 idx16[TT];                                  // 1 KB
    __shared__ u32 mbits[TT];                                  // 2 KB

    const int tid  = threadIdx.x;
    const int lane = tid & 63;
    const int wv   = tid >> 6;        // wave 0..7
    const int l15  = lane & 15;       // acc col
    const int c4   = lane >> 4;       // 0..3 (acc row group)
    const int d    = blockIdx.x & 1;  // 0 fwd, 1 bwd
    const int b0   = blockIdx.x >> 1; // chain 0..255
    const int rev  = d;

    const int q    = l15 & 3;         // acc row within c4 group (the dim)
    const bool fB  = (l15 >> 3) != 0; // role: A = state-owner, B = helper

    const float* Wih = d ? Wih_b : Wih_f;
    const float* Whh = d ? Whh_b : Whh_f;
    const float* bih = d ? bih_b : bih_f;
    const float* bhh = d ? bhh_b : bhh_f;

    // ---- init: idx (u16), mask bits, zero H buffers
    if (tid < TT) {
        idx16[tid] = (u16)idx[b0 * TT + tid];
        mbits[tid] = (masks[b0 * TT + tid] != 0.f) ? 1u : 0u;
    }
    for (int i = tid; i < 2 * 6 * 1024 / 4; i += 512)
        ((u32*)Hbuf)[i] = 0u;

    // ---- W fragments (A-operand) in VGPRs: w[kt][gt], gt = i/f/g/o.
    // Lane provides A[row = gate][k]: gate n = (wv + gt*8)*16 + l15,
    // k = kt*32 + c4*8 + j, j = 0..7.  (identical to R9-R13, proven)
    f16x8 w[6][4];
#pragma unroll
    for (int gt = 0; gt < 4; ++gt) {
        const int n = (wv + gt * 8) * 16 + l15;
        // kt = 0: k = c4*8 + j (< 32 < 50) -> Wih (float2 loads: 8B aligned)
#pragma unroll
        for (int jj = 0; jj < 4; ++jj) {
            const float2 e = *(const float2*)(Wih + n * 50 + c4 * 8 + jj * 2);
            w[0][gt][2 * jj]     = (f16)e.x;
            w[0][gt][2 * jj + 1] = (f16)e.y;
        }
        // kt = 1: k = 32 + c4*8 + j, real iff k < 50
#pragma unroll
        for (int j = 0; j < 8; ++j) {
            const int k = 32 + c4 * 8 + j;
            float v = 0.f;
            if (k < 50) v = Wih[n * 50 + k];
            w[1][gt][j] = (f16)v;
        }
        // kt = 2..5: k >= 64 -> Whh[n][k-64] (16B aligned float4 x2)
#pragma unroll
        for (int kt = 2; kt < 6; ++kt) {
            const int kh = (kt - 2) * 32 + c4 * 8;
            const float4 e0 = *(const float4*)(Whh + n * 128 + kh);
            const float4 e1 = *(const float4*)(Whh + n * 128 + kh + 4);
            w[kt][gt][0] = (f16)e0.x; w[kt][gt][1] = (f16)e0.y;
            w[kt][gt][2] = (f16)e0.z; w[kt][gt][3] = (f16)e0.w;
            w[kt][gt][4] = (f16)e1.x; w[kt][gt][5] = (f16)e1.y;
            w[kt][gt][6] = (f16)e1.z; w[kt][gt][7] = (f16)e1.w;
        }
    }

    // ---- per-lane biases for this lane's dim hd (post-MFMA add)
    const int hd  = wv * 16 + c4 * 4 + q;
    const float b_i = bih[hd]       + bhh[hd];
    const float b_f = bih[128 + hd] + bhh[128 + hd];
    const float b_g = bih[256 + hd] + bhh[256 + hd];
    const float b_o = bih[384 + hd] + bhh[384 + hd];

    __syncthreads();   // idx16/mbits/Hbuf-zero visible before x store

    // ---- x for step 0: threads 0..399, col pm = 0..15 (all copies of chain)
    if (tid < 400) {
        const int pm = tid / 25, ps = tid % 25;
        const int t0  = rev ? (TT - 1) : 0;
        const int row = idx16[t0];
        const float2 e = *(const float2*)(emb + row * 50 + ps * 2);
        const int k0 = 2 * ps;
        const int kt = k0 >> 5, c4k = (k0 >> 3) & 3, j = k0 & 7;
        *(u32*)(&Hbuf[0][(kt << 10) + ((c4k * 16 + pm) << 4) + (j << 1)]) =
            packh2(e.x, e.y);
    }
    __syncthreads();

    float cst0 = 0.f, rm0 = -3e38f;

    // h-writeback: dim-pair base hdp = hd & ~1; 8 holder-lanes per pair,
    // lane writes cols {2u, 2u+1}, u = ((l15>>2)<<1)|(l15&1) in 0..7.
    const int hdp    = hd & ~1;
    const int k0h    = 64 + hdp;
    const int wb_kt  = k0h >> 5;
    const int wb_c4k = (k0h >> 3) & 3;
    const int wb_j   = k0h & 7;              // even -> u32-aligned
    const int uu     = ((l15 >> 2) << 1) | (l15 & 1);
    const int wb_off = (wb_kt << 10) + ((wb_c4k * 16 + 2 * uu) << 4) + (wb_j << 1);

    for (int s = 0; s < TT; ++s) {
        const int cur = s & 1;
        const int t   = rev ? (TT - 1 - s) : s;

        // prefetch next step's x row-pair (hidden under MFMA)
        float2 e;
        int pk0 = 0;
        const bool pf = (tid < 400) && (s + 1 < TT);
        const int pm = tid / 25, ps = tid % 25;
        if (pf) {
            const int t1  = rev ? (TT - 2 - s) : (s + 1);
            const int row = idx16[t1];
            e = *(const float2*)(emb + row * 50 + ps * 2);
            pk0 = 2 * ps;
        }

        // ---- MFMA: 4 gate tiles x 6 K-steps; B-frag = contiguous 16B/lane
        const unsigned char* hb = &Hbuf[cur][0];
        const f32x4 z = {0.f, 0.f, 0.f, 0.f};
        f32x4 ai = z, af = z, ag = z, ao = z;
#pragma unroll
        for (int kt = 0; kt < 6; ++kt) {
            const f16x8 bf = *(const f16x8*)(hb + (kt << 10) + (lane << 4));
            ai = __builtin_amdgcn_mfma_f32_16x16x32_f16(w[kt][0], bf, ai, 0, 0, 0);
            af = __builtin_amdgcn_mfma_f32_16x16x32_f16(w[kt][1], bf, af, 0, 0, 0);
            ag = __builtin_amdgcn_mfma_f32_16x16x32_f16(w[kt][2], bf, ag, 0, 0, 0);
            ao = __builtin_amdgcn_mfma_f32_16x16x32_f16(w[kt][3], bf, ao, 0, 0, 0);
        }

        // ---- q-row select + bias (cols 16x duplicated)
        const float iv = sel4(ai, q) + b_i;
        const float fv = sel4(af, q) + b_f;
        const float gv = sel4(ag, q) + b_g;
        const float ov = sel4(ao, q) + b_o;

        // ---- SIMT role-split activation, DPP transport (R13, proven):
        // role A: su=sig(f), sv=sig(i); role B: su=sig(2g), sv=sig(o)
        const float u_in = fB ? (gv + gv) : fv;
        const float v_in = fB ? ov : iv;
        const float su = sigf(u_in);
        const float sv = sigf(v_in);
        const float tg_send = 2.f * su - 1.f;     // B: tanh(g); A: junk
        const float tgx = xor8(tg_send);          // A receives tanh(g)
        const float svx = xor8(sv);               // A receives sig(o)
        const float cc = su * cst0 + sv * tgx;    // A: valid c; B: junk chain
        cst0 = cc;
        const float ccx = xor8(cc);               // B receives A's cc
        const float cc_use = fB ? ccx : cc;
        const float th = 2.f * sigf(cc_use + cc_use) - 1.f;   // tanh(c) valid
        const float so_use = fB ? sv : svx;       // sig(o) in both roles
        const float hh = so_use * th;             // VALID in all lanes

        const float pen = (mbits[t] & 1u) ? 0.f : 1e8f;
        rm0 = fmaxf(rm0, hh - pen);

        // ---- writeback: pack dim-pair via DPP xor1, 2 aligned u32 writes
        unsigned char* nb = &Hbuf[cur ^ 1][0];
        {
            const float hx = xor1(hh);            // neighbor dim's h
            const u32 pk = (q & 1) ? packh2(hx, hh) : packh2(hh, hx);
            *(u32*)(nb + wb_off)      = pk;
            *(u32*)(nb + wb_off + 16) = pk;
        }
        if (pf) {
            const int kt = pk0 >> 5, c4k = (pk0 >> 3) & 3, j = pk0 & 7;
            *(u32*)(nb + (kt << 10) + ((c4k * 16 + pm) << 4) + (j << 1)) =
                packh2(e.x, e.y);
        }
        __syncthreads();
    }

    // ---- output: one lane per dim (role A, spare 0)
    if (l15 < 4) {
        out[b0 * 256 + d * 128 + hd] = rm0;
    }
}

extern "C" void kernel_launch(void* const* d_in, const int* in_sizes, int n_in,
                              void* d_out, int out_size, void* d_ws, size_t ws_size,
                              hipStream_t stream) {
    const int*   idx   = (const int*)d_in[0];
    const float* masks = (const float*)d_in[1];
    const float* emb   = (const float*)d_in[2];
    const float* Wih_f = (const float*)d_in[3];
    const float* Whh_f = (const float*)d_in[4];
    const float* bih_f = (const float*)d_in[5];
    const float* bhh_f = (const float*)d_in[6];
    const float* Wih_b = (const float*)d_in[7];
    const float* Whh_b = (const float*)d_in[8];
    const float* bih_b = (const float*)d_in[9];
    const float* bhh_b = (const float*)d_in[10];
    float* out = (float*)d_out;

    bilstm_mfma_ch1_kernel<<<dim3(512), dim3(512), 0, stream>>>(
        idx, masks, emb,
        Wih_f, Whh_f, bih_f, bhh_f,
        Wih_b, Whh_b, bih_b, bhh_b,
        out);
}

// Round 15
// 789.873 us; speedup vs baseline: 1.1922x; 1.1922x over previous
//
#include <hip/hip_runtime.h>
#include <hip/hip_fp16.h>

// Bidirectional char-LSTM + masked max-pool via MFMA, operand-swapped,
// CH=1 with 16x-duplicated B-columns, role-split activation (DPP xor8),
// dim-pair-packed writeback (DPP xor1), 2 BLOCKS PER CU.
// 512 blocks = 2 dirs x 256 chains; 8 waves x 512 threads.
// R14 proved 512 blocks co-schedule 2/CU (occ 46%) but waves_per_eu(4,4)
// made the allocator target 64 VGPR -> 96-reg weight array spilled (108 MB
// scratch writes). Empirical allocator behavior: occupancy hint "4" => 64
// VGPR target; hint (2,2) => ~120; plain launch_bounds(512) => 128 cap.
// R15 = R14 with plain __launch_bounds__(512): working set ~108 fits the
// 128 budget, no spill, 4 waves/SIMD x <=128 VGPR = full file = 2 blocks/CU.
// Lane map: l15 = q(2b) | spare(1b) | role(1b); role pair = l15^8 (DPP
// row_ror:8), hh valid in ALL lanes (B role computes sig(o)*tanh(cc_A)).
// Writeback: DPP quad_perm xor1 packs (h[even dim],h[odd dim]) into one u32;
// each of 8 holder-lanes writes 2 aligned ds_write_b32 (16 cols total).
// Per step: D'[512 gates][16 cols] = W[512][192] x H[192][16] via
// mfma_f32_16x16x32_f16; W static in VGPRs (24 f16x8/wave); H in LDS
// fragment-ordered (lane l reads bytes [l*16,l*16+16) -> conflict-free).
// One barrier per step.

#define TT 512

typedef _Float16 f16;
typedef _Float16 f16x8 __attribute__((ext_vector_type(8)));
typedef float f32x4 __attribute__((ext_vector_type(4)));
typedef unsigned int u32;
typedef unsigned short u16;

static __device__ __forceinline__ u32 packh2(float lo, float hi) {
    union { struct { f16 x, y; } h; u32 u; } cv;
    cv.h.x = (f16)lo; cv.h.y = (f16)hi;
    return cv.u;
}
static __device__ __forceinline__ float fexp(float x) {
    return __builtin_amdgcn_exp2f(x * 1.44269504088896341f);
}
static __device__ __forceinline__ float frcp(float x) {
    return __builtin_amdgcn_rcpf(x);
}
static __device__ __forceinline__ float sigf(float x) {
    return frcp(1.f + fexp(-x));
}
static __device__ __forceinline__ float xor8(float x) {
    // lane <-> lane^8: DPP row_ror:8 (rotate by 8 within rows of 16 == xor 8)
    union { float f; int i; } c; c.f = x;
    c.i = __builtin_amdgcn_mov_dpp(c.i, 0x128, 0xF, 0xF, false);
    return c.f;
}
static __device__ __forceinline__ float xor1(float x) {
    // lane <-> lane^1: DPP quad_perm(1,0,3,2) = 0xB1
    union { float f; int i; } c; c.f = x;
    c.i = __builtin_amdgcn_mov_dpp(c.i, 0xB1, 0xF, 0xF, false);
    return c.f;
}
static __device__ __forceinline__ float sel4(f32x4 v, int q) {
    // q in 0..3, compile-time indices in each arm (rule #20: no dyn index)
    return (q & 2) ? ((q & 1) ? v[3] : v[2]) : ((q & 1) ? v[1] : v[0]);
}

__global__ __launch_bounds__(512)
void bilstm_mfma_ch1b_kernel(const int* __restrict__ idx,
                             const float* __restrict__ masks,
                             const float* __restrict__ emb,
                             const float* __restrict__ Wih_f, const float* __restrict__ Whh_f,
                             const float* __restrict__ bih_f, const float* __restrict__ bhh_f,
                             const float* __restrict__ Wih_b, const float* __restrict__ Whh_b,
                             const float* __restrict__ bih_b, const float* __restrict__ bhh_b,
                             float* __restrict__ out)
{
    // Hbuf[buf][kt][c4k][col][j]: value = H[k = kt*32 + c4k*8 + j][col] fp16;
    // all 16 cols are copies of the single chain.
    __shared__ __align__(16) unsigned char Hbuf[2][6 * 1024];  // 12 KB
    __shared__ u16 idx16[TT];                                  // 1 KB
    __shared__ u32 mbits[TT];                                  // 2 KB

    const int tid  = threadIdx.x;
    const int lane = tid & 63;
    const int wv   = tid >> 6;        // wave 0..7
    const int l15  = lane & 15;       // acc col
    const int c4   = lane >> 4;       // 0..3 (acc row group)
    const int d    = blockIdx.x & 1;  // 0 fwd, 1 bwd
    const int b0   = blockIdx.x >> 1; // chain 0..255
    const int rev  = d;

    const int q    = l15 & 3;         // acc row within c4 group (the dim)
    const bool fB  = (l15 >> 3) != 0; // role: A = state-owner, B = helper

    const float* Wih = d ? Wih_b : Wih_f;
    const float* Whh = d ? Whh_b : Whh_f;
    const float* bih = d ? bih_b : bih_f;
    const float* bhh = d ? bhh_b : bhh_f;

    // ---- init: idx (u16), mask bits, zero H buffers
    if (tid < TT) {
        idx16[tid] = (u16)idx[b0 * TT + tid];
        mbits[tid] = (masks[b0 * TT + tid] != 0.f) ? 1u : 0u;
    }
    for (int i = tid; i < 2 * 6 * 1024 / 4; i += 512)
        ((u32*)Hbuf)[i] = 0u;

    // ---- W fragments (A-operand) in VGPRs: w[kt][gt], gt = i/f/g/o.
    // Lane provides A[row = gate][k]: gate n = (wv + gt*8)*16 + l15,
    // k = kt*32 + c4*8 + j, j = 0..7.  (identical to R9-R14, proven)
    f16x8 w[6][4];
#pragma unroll
    for (int gt = 0; gt < 4; ++gt) {
        const int n = (wv + gt * 8) * 16 + l15;
        // kt = 0: k = c4*8 + j (< 32 < 50) -> Wih (float2 loads: 8B aligned)
#pragma unroll
        for (int jj = 0; jj < 4; ++jj) {
            const float2 e = *(const float2*)(Wih + n * 50 + c4 * 8 + jj * 2);
            w[0][gt][2 * jj]     = (f16)e.x;
            w[0][gt][2 * jj + 1] = (f16)e.y;
        }
        // kt = 1: k = 32 + c4*8 + j, real iff k < 50
#pragma unroll
        for (int j = 0; j < 8; ++j) {
            const int k = 32 + c4 * 8 + j;
            float v = 0.f;
            if (k < 50) v = Wih[n * 50 + k];
            w[1][gt][j] = (f16)v;
        }
        // kt = 2..5: k >= 64 -> Whh[n][k-64] (16B aligned float4 x2)
#pragma unroll
        for (int kt = 2; kt < 6; ++kt) {
            const int kh = (kt - 2) * 32 + c4 * 8;
            const float4 e0 = *(const float4*)(Whh + n * 128 + kh);
            const float4 e1 = *(const float4*)(Whh + n * 128 + kh + 4);
            w[kt][gt][0] = (f16)e0.x; w[kt][gt][1] = (f16)e0.y;
            w[kt][gt][2] = (f16)e0.z; w[kt][gt][3] = (f16)e0.w;
            w[kt][gt][4] = (f16)e1.x; w[kt][gt][5] = (f16)e1.y;
            w[kt][gt][6] = (f16)e1.z; w[kt][gt][7] = (f16)e1.w;
        }
    }

    // ---- per-lane biases for this lane's dim hd (post-MFMA add)
    const int hd  = wv * 16 + c4 * 4 + q;
    const float b_i = bih[hd]       + bhh[hd];
    const float b_f = bih[128 + hd] + bhh[128 + hd];
    const float b_g = bih[256 + hd] + bhh[256 + hd];
    const float b_o = bih[384 + hd] + bhh[384 + hd];

    __syncthreads();   // idx16/mbits/Hbuf-zero visible before x store

    // ---- x for step 0: threads 0..399, col pm = 0..15 (all copies of chain)
    if (tid < 400) {
        const int pm = tid / 25, ps = tid % 25;
        const int t0  = rev ? (TT - 1) : 0;
        const int row = idx16[t0];
        const float2 e = *(const float2*)(emb + row * 50 + ps * 2);
        const int k0 = 2 * ps;
        const int kt = k0 >> 5, c4k = (k0 >> 3) & 3, j = k0 & 7;
        *(u32*)(&Hbuf[0][(kt << 10) + ((c4k * 16 + pm) << 4) + (j << 1)]) =
            packh2(e.x, e.y);
    }
    __syncthreads();

    float cst0 = 0.f, rm0 = -3e38f;

    // h-writeback: dim-pair base hdp = hd & ~1; 8 holder-lanes per pair,
    // lane writes cols {2u, 2u+1}, u = ((l15>>2)<<1)|(l15&1) in 0..7.
    const int hdp    = hd & ~1;
    const int k0h    = 64 + hdp;
    const int wb_kt  = k0h >> 5;
    const int wb_c4k = (k0h >> 3) & 3;
    const int wb_j   = k0h & 7;              // even -> u32-aligned
    const int uu     = ((l15 >> 2) << 1) | (l15 & 1);
    const int wb_off = (wb_kt << 10) + ((wb_c4k * 16 + 2 * uu) << 4) + (wb_j << 1);

    for (int s = 0; s < TT; ++s) {
        const int cur = s & 1;
        const int t   = rev ? (TT - 1 - s) : s;

        // prefetch next step's x row-pair (hidden under MFMA)
        float2 e;
        int pk0 = 0;
        const bool pf = (tid < 400) && (s + 1 < TT);
        const int pm = tid / 25, ps = tid % 25;
        if (pf) {
            const int t1  = rev ? (TT - 2 - s) : (s + 1);
            const int row = idx16[t1];
            e = *(const float2*)(emb + row * 50 + ps * 2);
            pk0 = 2 * ps;
        }

        // ---- MFMA: 4 gate tiles x 6 K-steps; B-frag = contiguous 16B/lane
        const unsigned char* hb = &Hbuf[cur][0];
        const f32x4 z = {0.f, 0.f, 0.f, 0.f};
        f32x4 ai = z, af = z, ag = z, ao = z;
#pragma unroll
        for (int kt = 0; kt < 6; ++kt) {
            const f16x8 bf = *(const f16x8*)(hb + (kt << 10) + (lane << 4));
            ai = __builtin_amdgcn_mfma_f32_16x16x32_f16(w[kt][0], bf, ai, 0, 0, 0);
            af = __builtin_amdgcn_mfma_f32_16x16x32_f16(w[kt][1], bf, af, 0, 0, 0);
            ag = __builtin_amdgcn_mfma_f32_16x16x32_f16(w[kt][2], bf, ag, 0, 0, 0);
            ao = __builtin_amdgcn_mfma_f32_16x16x32_f16(w[kt][3], bf, ao, 0, 0, 0);
        }

        // ---- q-row select + bias (cols 16x duplicated)
        const float iv = sel4(ai, q) + b_i;
        const float fv = sel4(af, q) + b_f;
        const float gv = sel4(ag, q) + b_g;
        const float ov = sel4(ao, q) + b_o;

        // ---- SIMT role-split activation, DPP transport (R13, proven):
        // role A: su=sig(f), sv=sig(i); role B: su=sig(2g), sv=sig(o)
        const float u_in = fB ? (gv + gv) : fv;
        const float v_in = fB ? ov : iv;
        const float su = sigf(u_in);
        const float sv = sigf(v_in);
        const float tg_send = 2.f * su - 1.f;     // B: tanh(g); A: junk
        const float tgx = xor8(tg_send);          // A receives tanh(g)
        const float svx = xor8(sv);               // A receives sig(o)
        const float cc = su * cst0 + sv * tgx;    // A: valid c; B: junk chain
        cst0 = cc;
        const float ccx = xor8(cc);               // B receives A's cc
        const float cc_use = fB ? ccx : cc;
        const float th = 2.f * sigf(cc_use + cc_use) - 1.f;   // tanh(c) valid
        const float so_use = fB ? sv : svx;       // sig(o) in both roles
        const float hh = so_use * th;             // VALID in all lanes

        const float pen = (mbits[t] & 1u) ? 0.f : 1e8f;
        rm0 = fmaxf(rm0, hh - pen);

        // ---- writeback: pack dim-pair via DPP xor1, 2 aligned u32 writes
        unsigned char* nb = &Hbuf[cur ^ 1][0];
        {
            const float hx = xor1(hh);            // neighbor dim's h
            const u32 pk = (q & 1) ? packh2(hx, hh) : packh2(hh, hx);
            *(u32*)(nb + wb_off)      = pk;
            *(u32*)(nb + wb_off + 16) = pk;
        }
        if (pf) {
            const int kt = pk0 >> 5, c4k = (pk0 >> 3) & 3, j = pk0 & 7;
            *(u32*)(nb + (kt << 10) + ((c4k * 16 + pm) << 4) + (j << 1)) =
                packh2(e.x, e.y);
        }
        __syncthreads();
    }

    // ---- output: one lane per dim (role A, spare 0)
    if (l15 < 4) {
        out[b0 * 256 + d * 128 + hd] = rm0;
    }
}

extern "C" void kernel_launch(void* const* d_in, const int* in_sizes, int n_in,
                              void* d_out, int out_size, void* d_ws, size_t ws_size,
                              hipStream_t stream) {
    const int*   idx   = (const int*)d_in[0];
    const float* masks = (const float*)d_in[1];
    const float* emb   = (const float*)d_in[2];
    const float* Wih_f = (const float*)d_in[3];
    const float* Whh_f = (const float*)d_in[4];
    const float* bih_f = (const float*)d_in[5];
    const float* bhh_f = (const float*)d_in[6];
    const float* Wih_b = (const float*)d_in[7];
    const float* Whh_b = (const float*)d_in[8];
    const float* bih_b = (const float*)d_in[9];
    const float* bhh_b = (const float*)d_in[10];
    float* out = (float*)d_out;

    bilstm_mfma_ch1b_kernel<<<dim3(512), dim3(512), 0, stream>>>(
        idx, masks, emb,
        Wih_f, Whh_f, bih_f, bhh_f,
        Wih_b, Whh_b, bih_b, bhh_b,
        out);
}

// Round 16
// 436.740 us; speedup vs baseline: 2.1561x; 1.8086x over previous
//
#include <hip/hip_runtime.h>
#include <hip/hip_fp16.h>

// Bidirectional char-LSTM + masked max-pool via MFMA — 16-wave GATE-SPLIT.
// 256 blocks = 2 dirs x 128 chain-pairs (CH=2), 1024 threads = 16 waves.
// R13-R15 lesson: 8-wave blocks with in-reg weights can never co-schedule
// 2/CU (weights 96 + acc 16 + misc > 128/wave); stalls (~40% of step) were
// unhidden at 2 waves/SIMD. R16: split GATES across wave halves ->
// waves 0-7 own i,f tiles; waves 8-15 own g,o tiles. Per-wave weights halve
// (12 frags = 48 VGPR) and the SIMD gets 4 waves at staggered phases.
// Per step: halves run 12 MFMAs each (K=192, 16 cols = 2 chains x 8 dup);
// half1 computes tanh(g),sig(o) (role-split lane pairs, DPP xor8) and posts
// packed f16x2 to a 1KB exch array; half0 computes sig(i),sig(f) in
// parallel; barrier; half0 finishes c/h + 8-dup writeback (R13 scheme),
// half1 stages x(t+1); barrier. Both roles keep valid c-state.
// H layout in LDS: fragment-ordered block-diag (lane l reads bytes
// [l*16,l*16+16) -> conflict-free broadcast), proven R9-R15.

#define TT 512
#define CH 2

typedef _Float16 f16;
typedef _Float16 f16x8 __attribute__((ext_vector_type(8)));
typedef float f32x4 __attribute__((ext_vector_type(4)));
typedef unsigned int u32;
typedef unsigned short u16;

static __device__ __forceinline__ u32 packh2(float lo, float hi) {
    union { struct { f16 x, y; } h; u32 u; } cv;
    cv.h.x = (f16)lo; cv.h.y = (f16)hi;
    return cv.u;
}
static __device__ __forceinline__ float unpk_lo(u32 u) {
    union { u32 u; struct { f16 x, y; } h; } cv; cv.u = u;
    return (float)cv.h.x;
}
static __device__ __forceinline__ float unpk_hi(u32 u) {
    union { u32 u; struct { f16 x, y; } h; } cv; cv.u = u;
    return (float)cv.h.y;
}
static __device__ __forceinline__ float fexp(float x) {
    return __builtin_amdgcn_exp2f(x * 1.44269504088896341f);
}
static __device__ __forceinline__ float frcp(float x) {
    return __builtin_amdgcn_rcpf(x);
}
static __device__ __forceinline__ float sigf(float x) {
    return frcp(1.f + fexp(-x));
}
static __device__ __forceinline__ float xor8(float x) {
    // lane <-> lane^8: DPP row_ror:8 (rotate within rows of 16 == xor 8)
    union { float f; int i; } c; c.f = x;
    c.i = __builtin_amdgcn_mov_dpp(c.i, 0x128, 0xF, 0xF, false);
    return c.f;
}
static __device__ __forceinline__ float sel4(f32x4 v, int q) {
    // q in 0..3, compile-time indices in each arm (no dynamic indexing)
    return (q & 2) ? ((q & 1) ? v[3] : v[2]) : ((q & 1) ? v[1] : v[0]);
}

__global__ __attribute__((amdgpu_flat_work_group_size(1024, 1024),
                          amdgpu_num_vgpr(128)))
void bilstm_gsplit_kernel(const int* __restrict__ idx,
                          const float* __restrict__ masks,
                          const float* __restrict__ emb,
                          const float* __restrict__ Wih_f, const float* __restrict__ Whh_f,
                          const float* __restrict__ bih_f, const float* __restrict__ bhh_f,
                          const float* __restrict__ Wih_b, const float* __restrict__ Whh_b,
                          const float* __restrict__ bih_b, const float* __restrict__ bhh_b,
                          float* __restrict__ out)
{
    // Hbuf[buf][kt][c4k][col][j]: H[k = kt*32 + c4k*8 + j][col] fp16;
    // col&1 = chain, 8 copies per chain.
    __shared__ __align__(16) unsigned char Hbuf[2][6 * 1024];  // 12 KB
    __shared__ u16 idx16[CH * TT];                             // 2 KB
    __shared__ u32 mbits[TT];                                  // 2 KB
    __shared__ u32 exch[CH * 128];                             // 1 KB: (tg,so)

    const int tid  = threadIdx.x;
    const int lane = tid & 63;
    const int wv   = tid >> 6;        // wave 0..15
    const int half = wv >> 3;         // 0: i/f + state; 1: g/o + x-stage
    const int wvh  = wv & 7;
    const int l15  = lane & 15;
    const int c4   = lane >> 4;
    const int d    = blockIdx.x & 1;  // 0 fwd, 1 bwd
    const int g    = blockIdx.x >> 1; // 0..127
    const int b0   = g * CH;
    const int rev  = d;

    const int chain = l15 & 1;
    const int q     = (l15 >> 1) & 3;
    const int role  = l15 >> 3;       // 0 = A, 1 = B (pair via xor8)

    const float* Wih = d ? Wih_b : Wih_f;
    const float* Whh = d ? Whh_b : Whh_f;
    const float* bih = d ? bih_b : bih_f;
    const float* bhh = d ? bhh_b : bhh_f;

    // ---- init: idx (u16), mask bits, zero H buffers
    for (int i = tid; i < CH * TT; i += 1024) {
        const int m = i >> 9, t = i & 511;
        idx16[i] = (u16)idx[(b0 + m) * TT + t];
    }
    if (tid < TT) {
        u32 mb = 0;
        for (int m = 0; m < CH; ++m)
            mb |= (masks[(b0 + m) * TT + tid] != 0.f ? 1u : 0u) << m;
        mbits[tid] = mb;
    }
    for (int i = tid; i < 2 * 6 * 1024 / 4; i += 1024)
        ((u32*)Hbuf)[i] = 0u;

    // ---- W fragments: this wave's 2 gate tiles.
    // half 0: tiles {i: rows [wvh*16,+16)}, {f: rows [128+wvh*16,+16)}
    // half 1: tiles {g: rows [256+wvh*16,+16)}, {o: rows [384+wvh*16,+16)}
    const int tb0 = half * 256 + wvh * 16;
    const int tb1 = tb0 + 128;
    f16x8 w[6][2];
    f32x4 bias4[2];
#pragma unroll
    for (int tt = 0; tt < 2; ++tt) {
        const int n = (tt ? tb1 : tb0) + l15;
        {
            const int nb_ = (tt ? tb1 : tb0) + c4 * 4;
            const float4 bi = *(const float4*)(bih + nb_);
            const float4 bh = *(const float4*)(bhh + nb_);
            bias4[tt][0] = bi.x + bh.x; bias4[tt][1] = bi.y + bh.y;
            bias4[tt][2] = bi.z + bh.z; bias4[tt][3] = bi.w + bh.w;
        }
        // kt = 0: k = c4*8 + j (< 32 < 50) -> Wih
#pragma unroll
        for (int jj = 0; jj < 4; ++jj) {
            const float2 e = *(const float2*)(Wih + n * 50 + c4 * 8 + jj * 2);
            w[0][tt][2 * jj]     = (f16)e.x;
            w[0][tt][2 * jj + 1] = (f16)e.y;
        }
        // kt = 1: k = 32 + c4*8 + j, real iff k < 50
#pragma unroll
        for (int j = 0; j < 8; ++j) {
            const int k = 32 + c4 * 8 + j;
            float v = 0.f;
            if (k < 50) v = Wih[n * 50 + k];
            w[1][tt][j] = (f16)v;
        }
        // kt = 2..5: k >= 64 -> Whh[n][k-64]
#pragma unroll
        for (int kt = 2; kt < 6; ++kt) {
            const int kh = (kt - 2) * 32 + c4 * 8;
            const float4 e0 = *(const float4*)(Whh + n * 128 + kh);
            const float4 e1 = *(const float4*)(Whh + n * 128 + kh + 4);
            w[kt][tt][0] = (f16)e0.x; w[kt][tt][1] = (f16)e0.y;
            w[kt][tt][2] = (f16)e0.z; w[kt][tt][3] = (f16)e0.w;
            w[kt][tt][4] = (f16)e1.x; w[kt][tt][5] = (f16)e1.y;
            w[kt][tt][6] = (f16)e1.z; w[kt][tt][7] = (f16)e1.w;
        }
    }

    __syncthreads();   // idx16/mbits/Hbuf-zero visible before x store

    // ---- x for step 0: threads 0..399, col pm = 0..15 (chain pm&1, 8 dup)
    if (tid < 400) {
        const int pm = tid / 25, ps = tid % 25;
        const int t0  = rev ? (TT - 1) : 0;
        const int row = idx16[(pm & 1) * TT + t0];
        const float2 e = *(const float2*)(emb + row * 50 + ps * 2);
        const int k0 = 2 * ps;
        const int kt = k0 >> 5, c4k = (k0 >> 3) & 3, j = k0 & 7;
        *(u32*)(&Hbuf[0][(kt << 10) + ((c4k * 16 + pm) << 4) + (j << 1)]) =
            packh2(e.x, e.y);
    }
    __syncthreads();

    float cst = 0.f, rm = -3e38f;

    // task dim + writeback/exchange addresses
    const int hd     = wvh * 16 + c4 * 4 + q;
    const int k0h    = 64 + hd;
    const int wb_kt  = k0h >> 5;
    const int wb_c4k = (k0h >> 3) & 3;
    const int wb_j   = k0h & 7;
    const int wb_off = (wb_kt << 10) + ((wb_c4k * 16 + chain) << 4) + (wb_j << 1)
                     + role * 128;   // role covers 4 of the 8 col copies
    const int ex     = chain * 128 + hd;

    // x-prefetch owners: waves 8..15, first 400 lanes
    const int  tid2  = tid - 512;
    const bool pfthr = (tid2 >= 0) && (tid2 < 400);
    const int  pm2   = pfthr ? (tid2 / 25) : 0;
    const int  ps2   = pfthr ? (tid2 % 25) : 0;

    for (int s = 0; s < TT; ++s) {
        const int cur = s & 1;
        const int t   = rev ? (TT - 1 - s) : s;

        // half1: issue next x global load early (consumed after barrier 1)
        float2 e;
        int pk0 = 0;
        const bool pf = pfthr && (s + 1 < TT);
        if (pf) {
            const int t1  = rev ? (TT - 2 - s) : (s + 1);
            const int row = idx16[(pm2 & 1) * TT + t1];
            e = *(const float2*)(emb + row * 50 + ps2 * 2);
            pk0 = 2 * ps2;
        }

        // ---- MFMA: 2 gate tiles x 6 K-steps (per-lane contiguous B-frag)
        const unsigned char* hb = &Hbuf[cur][0];
        f32x4 a0 = bias4[0], a1 = bias4[1];
#pragma unroll
        for (int kt = 0; kt < 6; ++kt) {
            const f16x8 bf = *(const f16x8*)(hb + (kt << 10) + (lane << 4));
            a0 = __builtin_amdgcn_mfma_f32_16x16x32_f16(w[kt][0], bf, a0, 0, 0, 0);
            a1 = __builtin_amdgcn_mfma_f32_16x16x32_f16(w[kt][1], bf, a1, 0, 0, 0);
        }
        const float v0 = sel4(a0, q);   // i (half0) / g (half1)
        const float v1 = sel4(a1, q);   // f (half0) / o (half1)

        // ---- role-split nonlinearity (1 trans/lane), DPP pair combine
        const bool rB = (role != 0);
        const float a_in = rB ? v1 : (half ? (v0 + v0) : v0);
        const float sraw = sigf(a_in);
        // A of half1 turns sig(2g) into tanh(g); everyone else keeps sigmoid
        const float sval = (half && !rB) ? (2.f * sraw - 1.f) : sraw;
        const float sx   = xor8(sval);

        if (half) {
            // A: tg=self, so=sx ; B: tg=sx, so=self. A posts the pair.
            const float tg = rB ? sx : sval;
            const float so = rB ? sval : sx;
            if (!rB) exch[ex] = packh2(tg, so);
        }
        // half0: si = sig(i), sf = sig(f) for BOTH roles
        const float si = rB ? sx : sval;
        const float sf = rB ? sval : sx;

        __syncthreads();   // barrier 1: exch visible

        unsigned char* nb = &Hbuf[cur ^ 1][0];
        if (!half) {
            const u32 ts = exch[ex];
            const float tg = unpk_lo(ts);
            const float so = unpk_hi(ts);
            const float cc = sf * cst + si * tg;
            cst = cc;
            const float th = 2.f * sigf(cc + cc) - 1.f;   // tanh(c)
            const float hh = so * th;
            const float pen = ((mbits[t] >> chain) & 1u) ? 0.f : 1e8f;
            rm = fmaxf(rm, hh - pen);
            // write this role's 4 col copies (u16 at +0,+32,+64,+96)
            const u32 pkv = packh2(hh, hh);
            *(u16*)(nb + wb_off)      = (u16)pkv;
            *(u16*)(nb + wb_off + 32) = (u16)pkv;
            *(u16*)(nb + wb_off + 64) = (u16)pkv;
            *(u16*)(nb + wb_off + 96) = (u16)pkv;
        } else if (pf) {
            const int kt = pk0 >> 5, c4k = (pk0 >> 3) & 3, j = pk0 & 7;
            *(u32*)(nb + (kt << 10) + ((c4k * 16 + pm2) << 4) + (j << 1)) =
                packh2(e.x, e.y);
        }
        __syncthreads();   // barrier 2: h + x visible for next step
    }

    // ---- output: half0, role A -> unique lane per (chain, dim)
    if (!half && !(l15 >> 3)) {
        out[(b0 + chain) * 256 + d * 128 + hd] = rm;
    }
}

extern "C" void kernel_launch(void* const* d_in, const int* in_sizes, int n_in,
                              void* d_out, int out_size, void* d_ws, size_t ws_size,
                              hipStream_t stream) {
    const int*   idx   = (const int*)d_in[0];
    const float* masks = (const float*)d_in[1];
    const float* emb   = (const float*)d_in[2];
    const float* Wih_f = (const float*)d_in[3];
    const float* Whh_f = (const float*)d_in[4];
    const float* bih_f = (const float*)d_in[5];
    const float* bhh_f = (const float*)d_in[6];
    const float* Wih_b = (const float*)d_in[7];
    const float* Whh_b = (const float*)d_in[8];
    const float* bih_b = (const float*)d_in[9];
    const float* bhh_b = (const float*)d_in[10];
    float* out = (float*)d_out;

    bilstm_gsplit_kernel<<<dim3(256), dim3(1024), 0, stream>>>(
        idx, masks, emb,
        Wih_f, Whh_f, bih_f, bhh_f,
        Wih_b, Whh_b, bih_b, bhh_b,
        out);
}

// Round 17
// 381.410 us; speedup vs baseline: 2.4689x; 1.1451x over previous
//
#include <hip/hip_runtime.h>
#include <hip/hip_fp16.h>

// Bidirectional char-LSTM + masked max-pool via MFMA — COMPACT H layout.
// 256 blocks = 2 dirs x 128 chain-pairs (CH=2), 512 threads, 8 waves.
// R9-R16 stored the H operand 8x-duplicated ("fragment-ordered") on the
// false assumption that B-frag reads need per-lane-contiguous storage.
// Same-address LDS reads BROADCAST (2-way aliasing free, m136) -> store H
// compactly: Hc[buf][chain][k=192] f16 (768B/buf). Lane reads its b128 at
// chain*384 + kt*64 + c4*16 (8 lanes share each address).
// Wins vs R13 (397us): h-writeback 8 copies -> 1 (DPP-xor2 pair-packed u32,
// 16 writer-lanes/wave); x-staging 400 lanes -> 50; bank conflicts ~18M -> ~0.
// MFMA scheme, role-split activation (DPP xor8), 1 barrier/step: unchanged.
// Per step: D'[512 gates][16 cols(2 chains alternating)] = W[512][192] x
// H[192][16]; W static in VGPRs (24 f16x8/wave); acc cols l15: chain=l15&1,
// q=(l15>>1)&3 (acc row), role=l15>>3 (activation pair via xor8).

#define TT 512
#define CH 2

typedef _Float16 f16;
typedef _Float16 f16x8 __attribute__((ext_vector_type(8)));
typedef float f32x4 __attribute__((ext_vector_type(4)));
typedef unsigned int u32;
typedef unsigned short u16;

static __device__ __forceinline__ u32 packh2(float lo, float hi) {
    union { struct { f16 x, y; } h; u32 u; } cv;
    cv.h.x = (f16)lo; cv.h.y = (f16)hi;
    return cv.u;
}
static __device__ __forceinline__ float fexp(float x) {
    return __builtin_amdgcn_exp2f(x * 1.44269504088896341f);
}
static __device__ __forceinline__ float frcp(float x) {
    return __builtin_amdgcn_rcpf(x);
}
static __device__ __forceinline__ float sigf(float x) {
    return frcp(1.f + fexp(-x));
}
static __device__ __forceinline__ float xor8(float x) {
    // lane <-> lane^8: DPP row_ror:8 (rotate within rows of 16 == xor 8)
    union { float f; int i; } c; c.f = x;
    c.i = __builtin_amdgcn_mov_dpp(c.i, 0x128, 0xF, 0xF, false);
    return c.f;
}
static __device__ __forceinline__ float xor2(float x) {
    // lane <-> lane^2: quad_perm(2,3,0,1) = 0x4E
    union { float f; int i; } c; c.f = x;
    c.i = __builtin_amdgcn_mov_dpp(c.i, 0x4E, 0xF, 0xF, false);
    return c.f;
}
static __device__ __forceinline__ float sel4(f32x4 v, int q) {
    // q in 0..3, compile-time indices in each arm (no dynamic indexing)
    return (q & 2) ? ((q & 1) ? v[3] : v[2]) : ((q & 1) ? v[1] : v[0]);
}

__global__ __attribute__((amdgpu_flat_work_group_size(512, 512),
                          amdgpu_waves_per_eu(2, 2)))
void bilstm_compact_kernel(const int* __restrict__ idx,
                           const float* __restrict__ masks,
                           const float* __restrict__ emb,
                           const float* __restrict__ Wih_f, const float* __restrict__ Whh_f,
                           const float* __restrict__ bih_f, const float* __restrict__ bhh_f,
                           const float* __restrict__ Wih_b, const float* __restrict__ Whh_b,
                           const float* __restrict__ bih_b, const float* __restrict__ bhh_b,
                           float* __restrict__ out)
{
    // Hc[buf][chain][k]: k 0..49 = x, 50..63 = 0 pad, 64..191 = h[k-64]
    __shared__ __align__(16) u16 Hc[2][CH][192];   // 1.5 KB
    __shared__ u16 idx16[CH * TT];                 // 2 KB
    __shared__ u32 mbits[TT];                      // 2 KB

    const int tid  = threadIdx.x;
    const int lane = tid & 63;
    const int wv   = tid >> 6;        // wave 0..7
    const int l15  = lane & 15;       // acc col
    const int c4   = lane >> 4;       // 0..3 (acc row group / B k-group)
    const int d    = blockIdx.x & 1;  // 0 fwd, 1 bwd
    const int g    = blockIdx.x >> 1; // 0..127
    const int b0   = g * CH;
    const int rev  = d;

    const int chain = l15 & 1;
    const int q     = (l15 >> 1) & 3; // acc row within c4 group
    const int role  = l15 >> 3;       // 0 = A (state-owner), 1 = B (helper)

    const float* Wih = d ? Wih_b : Wih_f;
    const float* Whh = d ? Whh_b : Whh_f;
    const float* bih = d ? bih_b : bih_f;
    const float* bhh = d ? bhh_b : bhh_f;

    // ---- init: idx (u16), mask bits, zero Hc (pads stay 0 forever)
    for (int i = tid; i < CH * TT; i += 512) {
        const int m = i >> 9, t = i & 511;
        idx16[i] = (u16)idx[(b0 + m) * TT + t];
    }
    if (tid < TT) {
        u32 mb = 0;
        for (int m = 0; m < CH; ++m)
            mb |= (masks[(b0 + m) * TT + tid] != 0.f ? 1u : 0u) << m;
        mbits[tid] = mb;
    }
    if (tid < 2 * CH * 192 / 2) {          // 384 u32s
        ((u32*)Hc)[tid] = 0u;
    }

    // ---- W fragments (A-operand) in VGPRs: w[kt][gt], gt = i/f/g/o.
    // Lane provides A[row = gate][k]: gate n = (wv + gt*8)*16 + l15,
    // k = kt*32 + c4*8 + j, j = 0..7.  (identical to R9-R16, proven)
    f16x8 w[6][4];
    f32x4 bias4[4];
#pragma unroll
    for (int gt = 0; gt < 4; ++gt) {
        const int n = (wv + gt * 8) * 16 + l15;
        {   // bias for acc rows: gates (wv+gt*8)*16 + c4*4 + q', q'=0..3
            const int nb_ = (wv + gt * 8) * 16 + c4 * 4;
            const float4 bi = *(const float4*)(bih + nb_);
            const float4 bh = *(const float4*)(bhh + nb_);
            bias4[gt][0] = bi.x + bh.x; bias4[gt][1] = bi.y + bh.y;
            bias4[gt][2] = bi.z + bh.z; bias4[gt][3] = bi.w + bh.w;
        }
        // kt = 0: k = c4*8 + j (< 32 < 50) -> Wih (float2 loads: 8B aligned)
#pragma unroll
        for (int jj = 0; jj < 4; ++jj) {
            const float2 e = *(const float2*)(Wih + n * 50 + c4 * 8 + jj * 2);
            w[0][gt][2 * jj]     = (f16)e.x;
            w[0][gt][2 * jj + 1] = (f16)e.y;
        }
        // kt = 1: k = 32 + c4*8 + j, real iff k < 50
#pragma unroll
        for (int j = 0; j < 8; ++j) {
            const int k = 32 + c4 * 8 + j;
            float v = 0.f;
            if (k < 50) v = Wih[n * 50 + k];
            w[1][gt][j] = (f16)v;
        }
        // kt = 2..5: k >= 64 -> Whh[n][k-64] (16B aligned float4 x2)
#pragma unroll
        for (int kt = 2; kt < 6; ++kt) {
            const int kh = (kt - 2) * 32 + c4 * 8;
            const float4 e0 = *(const float4*)(Whh + n * 128 + kh);
            const float4 e1 = *(const float4*)(Whh + n * 128 + kh + 4);
            w[kt][gt][0] = (f16)e0.x; w[kt][gt][1] = (f16)e0.y;
            w[kt][gt][2] = (f16)e0.z; w[kt][gt][3] = (f16)e0.w;
            w[kt][gt][4] = (f16)e1.x; w[kt][gt][5] = (f16)e1.y;
            w[kt][gt][6] = (f16)e1.z; w[kt][gt][7] = (f16)e1.w;
        }
    }

    __syncthreads();   // idx16/mbits/Hc-zero visible before x store

    // ---- x staging lanes: wave 7, 50 lanes (2 chains x 25 half-pairs)
    const int  tid7 = tid - 448;
    const bool xthr = (tid7 >= 0) && (tid7 < 50);
    const int  xch  = xthr ? (tid7 / 25) : 0;
    const int  xps  = xthr ? (tid7 % 25) : 0;

    // ---- x for step 0
    if (xthr) {
        const int t0  = rev ? (TT - 1) : 0;
        const int row = idx16[xch * TT + t0];
        const float2 e = *(const float2*)(emb + row * 50 + xps * 2);
        *(u32*)((unsigned char*)&Hc[0][0][0] + xch * 384 + xps * 4) =
            packh2(e.x, e.y);
    }
    __syncthreads();

    float cst = 0.f, rm = -3e38f;

    const int hd = wv * 16 + c4 * 4 + q;   // this lane's dim
    // writeback: lanes l15 in {0,1,4,5} (role 0, even q) write the dim-pair
    const bool wbthr = (l15 == 0) | (l15 == 1) | (l15 == 4) | (l15 == 5);

    for (int s = 0; s < TT; ++s) {
        const int cur = s & 1;
        const int t   = rev ? (TT - 1 - s) : s;

        // prefetch next step's x pair (wave 7; hidden under MFMA)
        float2 e;
        const bool pf = xthr && (s + 1 < TT);
        if (pf) {
            const int t1  = rev ? (TT - 2 - s) : (s + 1);
            const int row = idx16[xch * TT + t1];
            e = *(const float2*)(emb + row * 50 + xps * 2);
        }

        // ---- MFMA: 4 gate tiles x 6 K-steps; B-frag = broadcast b128 read
        const unsigned char* hb =
            (const unsigned char*)&Hc[cur][0][0] + chain * 384;
        f32x4 ai = bias4[0], af = bias4[1], ag = bias4[2], ao = bias4[3];
#pragma unroll
        for (int kt = 0; kt < 6; ++kt) {
            const f16x8 bf = *(const f16x8*)(hb + kt * 64 + c4 * 16);
            ai = __builtin_amdgcn_mfma_f32_16x16x32_f16(w[kt][0], bf, ai, 0, 0, 0);
            af = __builtin_amdgcn_mfma_f32_16x16x32_f16(w[kt][1], bf, af, 0, 0, 0);
            ag = __builtin_amdgcn_mfma_f32_16x16x32_f16(w[kt][2], bf, ag, 0, 0, 0);
            ao = __builtin_amdgcn_mfma_f32_16x16x32_f16(w[kt][3], bf, ao, 0, 0, 0);
        }

        // ---- q-row select (bias already in acc)
        const float iv = sel4(ai, q);
        const float fv = sel4(af, q);
        const float gv = sel4(ag, q);
        const float ov = sel4(ao, q);

        // ---- SIMT role-split activation, DPP transport (R13, proven):
        // role A: su=sig(f), sv=sig(i); role B: su=sig(2g), sv=sig(o)
        const bool rB = (role != 0);
        const float u_in = rB ? (gv + gv) : fv;
        const float v_in = rB ? ov : iv;
        const float su = sigf(u_in);
        const float sv = sigf(v_in);
        const float tg_send = 2.f * su - 1.f;     // B: tanh(g); A: junk
        const float tgx = xor8(tg_send);          // A receives tanh(g)
        const float svx = xor8(sv);               // A receives sig(o)
        const float cc = su * cst + sv * tgx;     // A: valid c; B: junk chain
        cst = cc;
        const float ccx = xor8(cc);               // B receives A's cc
        const float cc_use = rB ? ccx : cc;
        const float th = 2.f * sigf(cc_use + cc_use) - 1.f;   // tanh(c)
        const float so_use = rB ? sv : svx;       // sig(o) in both roles
        const float hh = so_use * th;             // VALID in all lanes

        const float pen = ((mbits[t] >> chain) & 1u) ? 0.f : 1e8f;
        rm = fmaxf(rm, hh - pen);

        // ---- writeback: single copy, dim-pair packed via DPP xor2
        unsigned char* nb = (unsigned char*)&Hc[cur ^ 1][0][0];
        const float hx2 = xor2(hh);               // neighbor dim's h (q^1)
        if (wbthr) {
            // this lane q even: pk = (h[hd], h[hd+1]); addr 4B-aligned
            *(u32*)(nb + chain * 384 + 128 + hd * 2) = packh2(hh, hx2);
        }
        if (pf) {
            *(u32*)(nb + xch * 384 + xps * 4) = packh2(e.x, e.y);
        }
        __syncthreads();
    }

    // ---- output: lanes l15 < 8 give unique (chain, q) -> one per dim
    if (l15 < 8) {
        out[(b0 + chain) * 256 + d * 128 + hd] = rm;
    }
}

extern "C" void kernel_launch(void* const* d_in, const int* in_sizes, int n_in,
                              void* d_out, int out_size, void* d_ws, size_t ws_size,
                              hipStream_t stream) {
    const int*   idx   = (const int*)d_in[0];
    const float* masks = (const float*)d_in[1];
    const float* emb   = (const float*)d_in[2];
    const float* Wih_f = (const float*)d_in[3];
    const float* Whh_f = (const float*)d_in[4];
    const float* bih_f = (const float*)d_in[5];
    const float* bhh_f = (const float*)d_in[6];
    const float* Wih_b = (const float*)d_in[7];
    const float* Whh_b = (const float*)d_in[8];
    const float* bih_b = (const float*)d_in[9];
    const float* bhh_b = (const float*)d_in[10];
    float* out = (float*)d_out;

    bilstm_compact_kernel<<<dim3(256), dim3(512), 0, stream>>>(
        idx, masks, emb,
        Wih_f, Whh_f, bih_f, bhh_f,
        Wih_b, Whh_b, bih_b, bhh_b,
        out);
}